// Round 1
// baseline (1062.690 us; speedup 1.0000x reference)
//
#include <hip/hip_runtime.h>
#include <hip/hip_bf16.h>

// ---------- types ----------
using short8 = __attribute__((ext_vector_type(8))) short;
using f32x4  = __attribute__((ext_vector_type(4))) float;

// f32 -> bf16 round-to-nearest-even
__device__ __forceinline__ unsigned short f2bf(float f) {
    union { float f; unsigned u; } x; x.f = f;
    unsigned r = x.u + 0x7FFFu + ((x.u >> 16) & 1u);
    return (unsigned short)(r >> 16);
}

// ---------- mask dtype detector ----------
// flag bit0: some u32 value >1 (not plain int32 0/1)
// flag bit1: some u32 value >1 and != 0x3F800000 (not f32 0.0/1.0) => 1-byte bool
__global__ void detect_mask_kernel(const unsigned int* __restrict__ m, int* __restrict__ flag) {
    if (threadIdx.x == 0) *flag = 0;
    __syncthreads();
    unsigned v = m[threadIdx.x];
    if (v > 1u) {
        atomicOr(flag, 1);
        if (v != 0x3F800000u) atomicOr(flag, 2);
    }
}

// ---------- transpose-convert W (f32 [k][n]) -> Wt (bf16 [n][k]), 1024x1024, z in 0..3 ----------
__global__ __launch_bounds__(256) void wconv_kernel(
    const float* __restrict__ W0, const float* __restrict__ W1,
    const float* __restrict__ W2, const float* __restrict__ W3,
    unsigned short* __restrict__ Wt)
{
    const int z = blockIdx.z;
    const float* W = (z == 0) ? W0 : ((z == 1) ? W1 : ((z == 2) ? W2 : W3));
    unsigned short* O = Wt + (size_t)z * 1024 * 1024;
    __shared__ float tile[64][68];
    const int t = threadIdx.x;
    const int k0 = blockIdx.x * 64, n0 = blockIdx.y * 64;
    const int rr = t >> 4, cc = t & 15;
#pragma unroll
    for (int i = 0; i < 4; i++) {
        int row = rr + i * 16;
        float4 v = *reinterpret_cast<const float4*>(W + (size_t)(k0 + row) * 1024 + n0 + cc * 4);
        *reinterpret_cast<float4*>(&tile[row][cc * 4]) = v;
    }
    __syncthreads();
#pragma unroll
    for (int i = 0; i < 4; i++) {
        int rn = rr + i * 16;
        ushort4 ov;
        ov.x = f2bf(tile[cc * 4 + 0][rn]);
        ov.y = f2bf(tile[cc * 4 + 1][rn]);
        ov.z = f2bf(tile[cc * 4 + 2][rn]);
        ov.w = f2bf(tile[cc * 4 + 3][rn]);
        *reinterpret_cast<ushort4*>(O + (size_t)(n0 + rn) * 1024 + k0 + cc * 4) = ov;
    }
}

// ---------- projection GEMM: Out_z = A_z (f32 8192x1024) @ W_z + b_z -> bf16 [b][h][n][64] ----------
__global__ __launch_bounds__(256) void proj_kernel(
    const float* __restrict__ Aq, const float* __restrict__ Ak, const float* __restrict__ Av,
    const unsigned short* __restrict__ Wt,   // [3][1024 n][1024 k] bf16
    const float* __restrict__ bq, const float* __restrict__ bk, const float* __restrict__ bv,
    unsigned short* __restrict__ Out)        // [3][8][16][1024][64]
{
    const int z = blockIdx.z;
    const float* A = (z == 0) ? Aq : ((z == 1) ? Ak : Av);
    const float* bias = (z == 0) ? bq : ((z == 1) ? bk : bv);
    const unsigned short* Wz = Wt + (size_t)z * 1024 * 1024;
    unsigned short* Oz = Out + (size_t)z * 8 * 16 * 1024 * 64;

    const int tid = threadIdx.x;
    const int w = tid >> 6, l = tid & 63;
    const int l16 = l & 15, g = l >> 4;
    const int rbase = blockIdx.x * 128 + w * 32;
    const int cbase = blockIdx.y * 64;

    f32x4 acc[2][4];
#pragma unroll
    for (int i = 0; i < 2; i++)
#pragma unroll
        for (int j = 0; j < 4; j++) acc[i][j] = (f32x4){0.f, 0.f, 0.f, 0.f};

#pragma unroll 2
    for (int k0 = 0; k0 < 1024; k0 += 32) {
        short8 a[2];
#pragma unroll
        for (int rf = 0; rf < 2; rf++) {
            const float* ap = A + (size_t)(rbase + rf * 16 + l16) * 1024 + k0 + g * 8;
            float4 v0 = *reinterpret_cast<const float4*>(ap);
            float4 v1 = *reinterpret_cast<const float4*>(ap + 4);
            short8 av;
            av[0] = (short)f2bf(v0.x); av[1] = (short)f2bf(v0.y);
            av[2] = (short)f2bf(v0.z); av[3] = (short)f2bf(v0.w);
            av[4] = (short)f2bf(v1.x); av[5] = (short)f2bf(v1.y);
            av[6] = (short)f2bf(v1.z); av[7] = (short)f2bf(v1.w);
            a[rf] = av;
        }
        short8 bfr[4];
#pragma unroll
        for (int cf = 0; cf < 4; cf++)
            bfr[cf] = *reinterpret_cast<const short8*>(Wz + (size_t)(cbase + cf * 16 + l16) * 1024 + k0 + g * 8);
#pragma unroll
        for (int rf = 0; rf < 2; rf++)
#pragma unroll
            for (int cf = 0; cf < 4; cf++)
                acc[rf][cf] = __builtin_amdgcn_mfma_f32_16x16x32_bf16(a[rf], bfr[cf], acc[rf][cf], 0, 0, 0);
    }

#pragma unroll
    for (int rf = 0; rf < 2; rf++)
#pragma unroll
        for (int cf = 0; cf < 4; cf++)
#pragma unroll
            for (int r = 0; r < 4; r++) {
                int row = rbase + rf * 16 + g * 4 + r;
                int col = cbase + cf * 16 + l16;
                float val = acc[rf][cf][r] + bias[col];
                int bb = row >> 10, n = row & 1023;
                int h = col >> 6, d = col & 63;
                Oz[(((size_t)(bb * 16 + h)) * 1024 + n) * 64 + d] = f2bf(val);
            }
}

// ---------- transpose V: Vs [bh][k][64 d] bf16 -> Vt [bh][64 d][1024 k] bf16 ----------
__global__ __launch_bounds__(256) void vtrans_kernel(
    const unsigned short* __restrict__ Vs, unsigned short* __restrict__ Vt)
{
    const int bh = blockIdx.y;
    const int k0 = blockIdx.x * 64;
    const unsigned short* In = Vs + (size_t)bh * 1024 * 64;
    unsigned short* O = Vt + (size_t)bh * 64 * 1024;
    __shared__ unsigned short tile[64][72];
    const int t = threadIdx.x;
    {
        const int row = t >> 3;
        const int c8 = (t & 7) * 8;
#pragma unroll
        for (int i = 0; i < 2; i++) {
            int r = row + i * 32;
            short8 v = *reinterpret_cast<const short8*>(In + (size_t)(k0 + r) * 64 + c8);
            *reinterpret_cast<short8*>(&tile[r][c8]) = v;
        }
    }
    __syncthreads();
    {
        const int rd = t >> 4, c4 = (t & 15) * 4;
#pragma unroll
        for (int i = 0; i < 4; i++) {
            int d = rd + i * 16;
            ushort4 ov;
            ov.x = tile[c4 + 0][d];
            ov.y = tile[c4 + 1][d];
            ov.z = tile[c4 + 2][d];
            ov.w = tile[c4 + 3][d];
            *reinterpret_cast<ushort4*>(O + (size_t)d * 1024 + k0 + c4) = ov;
        }
    }
}

// ---------- fused attention: per (b,h,64 q-rows): S=QK^T/8*w, mask, exp, PV, normalize ----------
__global__ __launch_bounds__(256) void attn_kernel(
    const unsigned short* __restrict__ Qs,   // [bh][1024][64]
    const unsigned short* __restrict__ Ks,   // [bh][1024][64]
    const unsigned short* __restrict__ Vt,   // [bh][64][1024]
    const float* __restrict__ attw,          // [bh][1024][1024]
    const void* __restrict__ mask,
    const int* __restrict__ flag,
    unsigned short* __restrict__ AO)         // [b][q][h*64+d] bf16
{
    const int b = blockIdx.z, h = blockIdx.y;
    const int qbase = blockIdx.x * 64;
    const int tid = threadIdx.x, w = tid >> 6, l = tid & 63, l16 = l & 15, g = l >> 4;
    const int bh = b * 16 + h;
    const unsigned short* Qbh = Qs + (size_t)bh * 1024 * 64;
    const unsigned short* Kbh = Ks + (size_t)bh * 1024 * 64;
    const unsigned short* Vbh = Vt + (size_t)bh * 64 * 1024;
    const float* wbh = attw + (size_t)bh * 1024 * 1024;
    const unsigned char* m8 = (const unsigned char*)mask;
    const unsigned int* m32 = (const unsigned int*)mask;
    const size_t mbase = (size_t)bh * 1024 * 1024;
    const bool bytemask = ((*flag) & 2) != 0;

    __shared__ unsigned short P[4][16][72];

    short8 qf[2];
#pragma unroll
    for (int ks = 0; ks < 2; ks++)
        qf[ks] = *reinterpret_cast<const short8*>(Qbh + (size_t)(qbase + w * 16 + l16) * 64 + ks * 32 + g * 8);

    f32x4 accO[4];
    float den[4] = {0.f, 0.f, 0.f, 0.f};
#pragma unroll
    for (int j = 0; j < 4; j++) accO[j] = (f32x4){0.f, 0.f, 0.f, 0.f};

    for (int kt = 0; kt < 16; kt++) {
        const int kb = kt * 64;
        f32x4 s[4];
#pragma unroll
        for (int j = 0; j < 4; j++) s[j] = (f32x4){0.f, 0.f, 0.f, 0.f};
#pragma unroll
        for (int cf = 0; cf < 4; cf++) {
#pragma unroll
            for (int ks = 0; ks < 2; ks++) {
                short8 kf = *reinterpret_cast<const short8*>(
                    Kbh + (size_t)(kb + cf * 16 + l16) * 64 + ks * 32 + g * 8);
                s[cf] = __builtin_amdgcn_mfma_f32_16x16x32_bf16(qf[ks], kf, s[cf], 0, 0, 0);
            }
        }
        __syncthreads();   // WAR: all PV reads of previous tile done before overwriting P
#pragma unroll
        for (int cf = 0; cf < 4; cf++) {
#pragma unroll
            for (int r = 0; r < 4; r++) {
                int qrow = qbase + w * 16 + g * 4 + r;
                int kcol = kb + cf * 16 + l16;
                size_t idx = (size_t)qrow * 1024 + kcol;
                float wv = wbh[idx];
                bool mk = bytemask ? (m8[mbase + idx] != 0) : (m32[mbase + idx] != 0u);
                float p = mk ? 0.0f : __expf(s[cf][r] * 0.125f * wv);
                den[r] += p;
                P[w][g * 4 + r][cf * 16 + l16] = f2bf(p);
            }
        }
        __syncthreads();   // RAW: P visible before PV reads
#pragma unroll
        for (int ks = 0; ks < 2; ks++) {
            short8 pf = *reinterpret_cast<const short8*>(&P[w][l16][ks * 32 + g * 8]);
#pragma unroll
            for (int cf = 0; cf < 4; cf++) {
                short8 vf = *reinterpret_cast<const short8*>(
                    Vbh + (size_t)(cf * 16 + l16) * 1024 + kb + ks * 32 + g * 8);
                accO[cf] = __builtin_amdgcn_mfma_f32_16x16x32_bf16(pf, vf, accO[cf], 0, 0, 0);
            }
        }
    }

#pragma unroll
    for (int r = 0; r < 4; r++) {
        float d = den[r];
        d += __shfl_xor(d, 1);
        d += __shfl_xor(d, 2);
        d += __shfl_xor(d, 4);
        d += __shfl_xor(d, 8);
        den[r] = d;
    }
#pragma unroll
    for (int cf = 0; cf < 4; cf++)
#pragma unroll
        for (int r = 0; r < 4; r++) {
            int qrow = qbase + w * 16 + g * 4 + r;
            int col = h * 64 + cf * 16 + l16;
            float val = accO[cf][r] / den[r];
            AO[((size_t)b * 1024 + qrow) * 1024 + col] = f2bf(val);
        }
}

// ---------- output projection: d_out = AO (bf16 8192x1024) @ Wo + bo (f32 out) ----------
__global__ __launch_bounds__(256) void outproj_kernel(
    const unsigned short* __restrict__ Ain,  // [8192][1024] bf16
    const unsigned short* __restrict__ Wto,  // [1024 n][1024 k] bf16
    const float* __restrict__ bo,
    float* __restrict__ Out)                 // [8192][1024] f32
{
    const int tid = threadIdx.x;
    const int w = tid >> 6, l = tid & 63;
    const int l16 = l & 15, g = l >> 4;
    const int rbase = blockIdx.x * 128 + w * 32;
    const int cbase = blockIdx.y * 64;

    f32x4 acc[2][4];
#pragma unroll
    for (int i = 0; i < 2; i++)
#pragma unroll
        for (int j = 0; j < 4; j++) acc[i][j] = (f32x4){0.f, 0.f, 0.f, 0.f};

#pragma unroll 2
    for (int k0 = 0; k0 < 1024; k0 += 32) {
        short8 a[2];
#pragma unroll
        for (int rf = 0; rf < 2; rf++)
            a[rf] = *reinterpret_cast<const short8*>(Ain + (size_t)(rbase + rf * 16 + l16) * 1024 + k0 + g * 8);
        short8 bfr[4];
#pragma unroll
        for (int cf = 0; cf < 4; cf++)
            bfr[cf] = *reinterpret_cast<const short8*>(Wto + (size_t)(cbase + cf * 16 + l16) * 1024 + k0 + g * 8);
#pragma unroll
        for (int rf = 0; rf < 2; rf++)
#pragma unroll
            for (int cf = 0; cf < 4; cf++)
                acc[rf][cf] = __builtin_amdgcn_mfma_f32_16x16x32_bf16(a[rf], bfr[cf], acc[rf][cf], 0, 0, 0);
    }

#pragma unroll
    for (int rf = 0; rf < 2; rf++)
#pragma unroll
        for (int cf = 0; cf < 4; cf++)
#pragma unroll
            for (int r = 0; r < 4; r++) {
                int row = rbase + rf * 16 + g * 4 + r;
                int col = cbase + cf * 16 + l16;
                Out[(size_t)row * 1024 + col] = acc[rf][cf][r] + bo[col];
            }
}

extern "C" void kernel_launch(void* const* d_in, const int* in_sizes, int n_in,
                              void* d_out, int out_size, void* d_ws, size_t ws_size,
                              hipStream_t stream)
{
    const float* queries = (const float*)d_in[0];
    const float* keys    = (const float*)d_in[1];
    const float* values  = (const float*)d_in[2];
    const void*  mask    = d_in[3];
    const float* attw    = (const float*)d_in[4];
    const float* Wq = (const float*)d_in[5];
    const float* bq = (const float*)d_in[6];
    const float* Wk = (const float*)d_in[7];
    const float* bk = (const float*)d_in[8];
    const float* Wv = (const float*)d_in[9];
    const float* bv = (const float*)d_in[10];
    const float* Wo = (const float*)d_in[11];
    const float* bo = (const float*)d_in[12];

    char* ws = (char*)d_ws;
    int* flag = (int*)ws;
    unsigned short* base = (unsigned short*)(ws + 256);
    const size_t M8 = (size_t)8 * 1024 * 1024;   // elements per 16MB bf16 buffer
    unsigned short* Qs = base;
    unsigned short* Ksb = base + M8;
    unsigned short* Vs = base + 2 * M8;
    unsigned short* Vtb = base + 3 * M8;
    unsigned short* AO = base + 4 * M8;
    unsigned short* Wt = base + 5 * M8;          // 4 x 1M elements

    detect_mask_kernel<<<1, 256, 0, stream>>>((const unsigned int*)mask, flag);
    wconv_kernel<<<dim3(16, 16, 4), 256, 0, stream>>>(Wq, Wk, Wv, Wo, Wt);
    proj_kernel<<<dim3(64, 16, 3), 256, 0, stream>>>(queries, keys, values, Wt, bq, bk, bv, Qs);
    vtrans_kernel<<<dim3(16, 128), 256, 0, stream>>>(Vs, Vtb);
    attn_kernel<<<dim3(16, 16, 8), 256, 0, stream>>>(Qs, Ksb, Vtb, attw, mask, flag, AO);
    outproj_kernel<<<dim3(64, 16), 256, 0, stream>>>(AO, Wt + (size_t)3 * 1024 * 1024, bo, (float*)d_out);
}

// Round 2
// 802.530 us; speedup vs baseline: 1.3242x; 1.3242x over previous
//
#include <hip/hip_runtime.h>
#include <hip/hip_bf16.h>

// ---------- types ----------
using short8 = __attribute__((ext_vector_type(8))) short;
using f32x4  = __attribute__((ext_vector_type(4))) float;

// f32 -> bf16 round-to-nearest-even
__device__ __forceinline__ unsigned short f2bf(float f) {
    union { float f; unsigned u; } x; x.f = f;
    unsigned r = x.u + 0x7FFFu + ((x.u >> 16) & 1u);
    return (unsigned short)(r >> 16);
}

// ---------- mask dtype detector ----------
// flag bit0: some u32 >1 (not int32 0/1); bit1: some u32 >1 and != 0x3F800000 (=> byte bool)
__global__ void detect_mask_kernel(const unsigned int* __restrict__ m, int* __restrict__ flag) {
    if (threadIdx.x == 0) *flag = 0;
    __syncthreads();
    unsigned v = m[threadIdx.x];
    if (v > 1u) {
        atomicOr(flag, 1);
        if (v != 0x3F800000u) atomicOr(flag, 2);
    }
}

// ---------- transpose-convert W (f32 [k][n]) -> Wt (bf16 [n][k]), 1024x1024, z in 0..3 ----------
__global__ __launch_bounds__(256) void wconv_kernel(
    const float* __restrict__ W0, const float* __restrict__ W1,
    const float* __restrict__ W2, const float* __restrict__ W3,
    unsigned short* __restrict__ Wt)
{
    const int z = blockIdx.z;
    const float* W = (z == 0) ? W0 : ((z == 1) ? W1 : ((z == 2) ? W2 : W3));
    unsigned short* O = Wt + (size_t)z * 1024 * 1024;
    __shared__ float tile[64][68];
    const int t = threadIdx.x;
    const int k0 = blockIdx.x * 64, n0 = blockIdx.y * 64;
    const int rr = t >> 4, cc = t & 15;
#pragma unroll
    for (int i = 0; i < 4; i++) {
        int row = rr + i * 16;
        float4 v = *reinterpret_cast<const float4*>(W + (size_t)(k0 + row) * 1024 + n0 + cc * 4);
        *reinterpret_cast<float4*>(&tile[row][cc * 4]) = v;
    }
    __syncthreads();
#pragma unroll
    for (int i = 0; i < 4; i++) {
        int rn = rr + i * 16;
        ushort4 ov;
        ov.x = f2bf(tile[cc * 4 + 0][rn]);
        ov.y = f2bf(tile[cc * 4 + 1][rn]);
        ov.z = f2bf(tile[cc * 4 + 2][rn]);
        ov.w = f2bf(tile[cc * 4 + 3][rn]);
        *reinterpret_cast<ushort4*>(O + (size_t)(n0 + rn) * 1024 + k0 + cc * 4) = ov;
    }
}

// ---------- convert f32 A -> bf16 A, 3 x 8M elements ----------
__global__ __launch_bounds__(256) void aconv_kernel(
    const float* __restrict__ Aq, const float* __restrict__ Ak, const float* __restrict__ Av,
    unsigned short* __restrict__ Out)
{
    const int z = blockIdx.y;
    const float* A = (z == 0) ? Aq : ((z == 1) ? Ak : Av);
    unsigned short* O = Out + (size_t)z * 8192 * 1024;
    size_t i = ((size_t)blockIdx.x * 256 + threadIdx.x) * 8;
    float4 v0 = *reinterpret_cast<const float4*>(A + i);
    float4 v1 = *reinterpret_cast<const float4*>(A + i + 4);
    short8 o;
    o[0] = (short)f2bf(v0.x); o[1] = (short)f2bf(v0.y);
    o[2] = (short)f2bf(v0.z); o[3] = (short)f2bf(v0.w);
    o[4] = (short)f2bf(v1.x); o[5] = (short)f2bf(v1.y);
    o[6] = (short)f2bf(v1.z); o[7] = (short)f2bf(v1.w);
    *reinterpret_cast<short8*>(O + i) = o;
}

// ---------- projection GEMM (bf16 A): Out_z = A_z @ W_z + b_z -> bf16 [b][h][n][64] ----------
__global__ __launch_bounds__(256) void proj_bf_kernel(
    const unsigned short* __restrict__ Abf,  // [3][8192][1024] bf16
    const unsigned short* __restrict__ Wt,   // [3][1024 n][1024 k] bf16
    const float* __restrict__ bq, const float* __restrict__ bk, const float* __restrict__ bv,
    unsigned short* __restrict__ Out)        // [3][8][16][1024][64]
{
    const int z = blockIdx.z;
    const unsigned short* A = Abf + (size_t)z * 8192 * 1024;
    const float* bias = (z == 0) ? bq : ((z == 1) ? bk : bv);
    const unsigned short* Wz = Wt + (size_t)z * 1024 * 1024;
    unsigned short* Oz = Out + (size_t)z * 8 * 16 * 1024 * 64;

    const int tid = threadIdx.x;
    const int w = tid >> 6, l = tid & 63;
    const int l16 = l & 15, g = l >> 4;
    const int rbase = blockIdx.x * 128 + w * 32;
    const int cbase = blockIdx.y * 64;

    f32x4 acc[2][4];
#pragma unroll
    for (int i = 0; i < 2; i++)
#pragma unroll
        for (int j = 0; j < 4; j++) acc[i][j] = (f32x4){0.f, 0.f, 0.f, 0.f};

#pragma unroll 2
    for (int k0 = 0; k0 < 1024; k0 += 32) {
        short8 a[2];
#pragma unroll
        for (int rf = 0; rf < 2; rf++)
            a[rf] = *reinterpret_cast<const short8*>(A + (size_t)(rbase + rf * 16 + l16) * 1024 + k0 + g * 8);
        short8 bfr[4];
#pragma unroll
        for (int cf = 0; cf < 4; cf++)
            bfr[cf] = *reinterpret_cast<const short8*>(Wz + (size_t)(cbase + cf * 16 + l16) * 1024 + k0 + g * 8);
#pragma unroll
        for (int rf = 0; rf < 2; rf++)
#pragma unroll
            for (int cf = 0; cf < 4; cf++)
                acc[rf][cf] = __builtin_amdgcn_mfma_f32_16x16x32_bf16(a[rf], bfr[cf], acc[rf][cf], 0, 0, 0);
    }

#pragma unroll
    for (int rf = 0; rf < 2; rf++)
#pragma unroll
        for (int cf = 0; cf < 4; cf++)
#pragma unroll
            for (int r = 0; r < 4; r++) {
                int row = rbase + rf * 16 + g * 4 + r;
                int col = cbase + cf * 16 + l16;
                float val = acc[rf][cf][r] + bias[col];
                int bb = row >> 10, n = row & 1023;
                int h = col >> 6, d = col & 63;
                Oz[(((size_t)(bb * 16 + h)) * 1024 + n) * 64 + d] = f2bf(val);
            }
}

// ---------- projection GEMM (f32 A fallback, converts in-loop) ----------
__global__ __launch_bounds__(256) void proj_f32_kernel(
    const float* __restrict__ Aq, const float* __restrict__ Ak, const float* __restrict__ Av,
    const unsigned short* __restrict__ Wt,
    const float* __restrict__ bq, const float* __restrict__ bk, const float* __restrict__ bv,
    unsigned short* __restrict__ Out)
{
    const int z = blockIdx.z;
    const float* A = (z == 0) ? Aq : ((z == 1) ? Ak : Av);
    const float* bias = (z == 0) ? bq : ((z == 1) ? bk : bv);
    const unsigned short* Wz = Wt + (size_t)z * 1024 * 1024;
    unsigned short* Oz = Out + (size_t)z * 8 * 16 * 1024 * 64;

    const int tid = threadIdx.x;
    const int w = tid >> 6, l = tid & 63;
    const int l16 = l & 15, g = l >> 4;
    const int rbase = blockIdx.x * 128 + w * 32;
    const int cbase = blockIdx.y * 64;

    f32x4 acc[2][4];
#pragma unroll
    for (int i = 0; i < 2; i++)
#pragma unroll
        for (int j = 0; j < 4; j++) acc[i][j] = (f32x4){0.f, 0.f, 0.f, 0.f};

#pragma unroll 2
    for (int k0 = 0; k0 < 1024; k0 += 32) {
        short8 a[2];
#pragma unroll
        for (int rf = 0; rf < 2; rf++) {
            const float* ap = A + (size_t)(rbase + rf * 16 + l16) * 1024 + k0 + g * 8;
            float4 v0 = *reinterpret_cast<const float4*>(ap);
            float4 v1 = *reinterpret_cast<const float4*>(ap + 4);
            short8 av;
            av[0] = (short)f2bf(v0.x); av[1] = (short)f2bf(v0.y);
            av[2] = (short)f2bf(v0.z); av[3] = (short)f2bf(v0.w);
            av[4] = (short)f2bf(v1.x); av[5] = (short)f2bf(v1.y);
            av[6] = (short)f2bf(v1.z); av[7] = (short)f2bf(v1.w);
            a[rf] = av;
        }
        short8 bfr[4];
#pragma unroll
        for (int cf = 0; cf < 4; cf++)
            bfr[cf] = *reinterpret_cast<const short8*>(Wz + (size_t)(cbase + cf * 16 + l16) * 1024 + k0 + g * 8);
#pragma unroll
        for (int rf = 0; rf < 2; rf++)
#pragma unroll
            for (int cf = 0; cf < 4; cf++)
                acc[rf][cf] = __builtin_amdgcn_mfma_f32_16x16x32_bf16(a[rf], bfr[cf], acc[rf][cf], 0, 0, 0);
    }

#pragma unroll
    for (int rf = 0; rf < 2; rf++)
#pragma unroll
        for (int cf = 0; cf < 4; cf++)
#pragma unroll
            for (int r = 0; r < 4; r++) {
                int row = rbase + rf * 16 + g * 4 + r;
                int col = cbase + cf * 16 + l16;
                float val = acc[rf][cf][r] + bias[col];
                int bb = row >> 10, n = row & 1023;
                int h = col >> 6, d = col & 63;
                Oz[(((size_t)(bb * 16 + h)) * 1024 + n) * 64 + d] = f2bf(val);
            }
}

// ---------- transpose V: Vs [bh][k][64 d] -> Vt [bh][64 d][1024 k] ----------
__global__ __launch_bounds__(256) void vtrans_kernel(
    const unsigned short* __restrict__ Vs, unsigned short* __restrict__ Vt)
{
    const int bh = blockIdx.y;
    const int k0 = blockIdx.x * 64;
    const unsigned short* In = Vs + (size_t)bh * 1024 * 64;
    unsigned short* O = Vt + (size_t)bh * 64 * 1024;
    __shared__ unsigned short tile[64][72];
    const int t = threadIdx.x;
    {
        const int row = t >> 3;
        const int c8 = (t & 7) * 8;
#pragma unroll
        for (int i = 0; i < 2; i++) {
            int r = row + i * 32;
            short8 v = *reinterpret_cast<const short8*>(In + (size_t)(k0 + r) * 64 + c8);
            *reinterpret_cast<short8*>(&tile[r][c8]) = v;
        }
    }
    __syncthreads();
    {
        const int rd = t >> 4, c4 = (t & 15) * 4;
#pragma unroll
        for (int i = 0; i < 4; i++) {
            int d = rd + i * 16;
            ushort4 ov;
            ov.x = tile[c4 + 0][d];
            ov.y = tile[c4 + 1][d];
            ov.z = tile[c4 + 2][d];
            ov.w = tile[c4 + 3][d];
            *reinterpret_cast<ushort4*>(O + (size_t)d * 1024 + k0 + c4) = ov;
        }
    }
}

// ---------- fused attention with transposed QK^T (S^T fragments -> vectorized attw/mask) ----------
__global__ __launch_bounds__(256) void attn_kernel(
    const unsigned short* __restrict__ Qs,   // [bh][1024][64]
    const unsigned short* __restrict__ Ks,   // [bh][1024][64]
    const unsigned short* __restrict__ Vt,   // [bh][64][1024]
    const float* __restrict__ attw,          // [bh][1024][1024]
    const void* __restrict__ mask,
    const int* __restrict__ flag,
    unsigned short* __restrict__ AO)         // [b][q][h*64+d] bf16
{
    const int b = blockIdx.z, h = blockIdx.y;
    const int qbase = blockIdx.x * 64;
    const int tid = threadIdx.x, w = tid >> 6, l = tid & 63, l16 = l & 15, g = l >> 4;
    const int bh = b * 16 + h;
    const unsigned short* Qbh = Qs + (size_t)bh * 1024 * 64;
    const unsigned short* Kbh = Ks + (size_t)bh * 1024 * 64;
    const unsigned short* Vbh = Vt + (size_t)bh * 64 * 1024;
    const bool bytemask = ((*flag) & 2) != 0;

    // per-lane row pointers (q-row = l16 within this wave's 16-row block)
    const int myq = qbase + w * 16 + l16;
    const float* wrow = attw + (size_t)bh * 1024 * 1024 + (size_t)myq * 1024;
    const unsigned char* mrow8 = (const unsigned char*)mask + (size_t)bh * 1024 * 1024 + (size_t)myq * 1024;
    const unsigned int* mrow32 = (const unsigned int*)mask + (size_t)bh * 1024 * 1024 + (size_t)myq * 1024;

    __shared__ unsigned short P[4][16][72];   // per-wave private: [q 16][k 64] (padded)

    short8 qf[2];
#pragma unroll
    for (int ks = 0; ks < 2; ks++)
        qf[ks] = *reinterpret_cast<const short8*>(Qbh + (size_t)myq * 64 + ks * 32 + g * 8);

    f32x4 accO[4];
    float den = 0.f;
#pragma unroll
    for (int j = 0; j < 4; j++) accO[j] = (f32x4){0.f, 0.f, 0.f, 0.f};

    for (int kt = 0; kt < 16; kt++) {
        const int kb = kt * 64;
        // S^T: s[cf] holds k-cols kb+cf*16+g*4+r (r=0..3) for q-row = l16's row
        f32x4 s[4];
#pragma unroll
        for (int j = 0; j < 4; j++) s[j] = (f32x4){0.f, 0.f, 0.f, 0.f};
#pragma unroll
        for (int cf = 0; cf < 4; cf++) {
#pragma unroll
            for (int ks = 0; ks < 2; ks++) {
                short8 kf = *reinterpret_cast<const short8*>(
                    Kbh + (size_t)(kb + cf * 16 + l16) * 64 + ks * 32 + g * 8);
                s[cf] = __builtin_amdgcn_mfma_f32_16x16x32_bf16(kf, qf[ks], s[cf], 0, 0, 0);
            }
        }
        // softmax numerators: vectorized attw (float4) + mask (uchar4/uint4) loads
#pragma unroll
        for (int cf = 0; cf < 4; cf++) {
            const int kcol = kb + cf * 16 + g * 4;
            float4 wv = *reinterpret_cast<const float4*>(wrow + kcol);
            float p0, p1, p2, p3;
            if (bytemask) {
                unsigned mm = *reinterpret_cast<const unsigned*>(mrow8 + kcol);
                p0 = (mm & 0x000000FFu) ? 0.f : __expf(s[cf][0] * 0.125f * wv.x);
                p1 = (mm & 0x0000FF00u) ? 0.f : __expf(s[cf][1] * 0.125f * wv.y);
                p2 = (mm & 0x00FF0000u) ? 0.f : __expf(s[cf][2] * 0.125f * wv.z);
                p3 = (mm & 0xFF000000u) ? 0.f : __expf(s[cf][3] * 0.125f * wv.w);
            } else {
                uint4 mm = *reinterpret_cast<const uint4*>(mrow32 + kcol);
                p0 = mm.x ? 0.f : __expf(s[cf][0] * 0.125f * wv.x);
                p1 = mm.y ? 0.f : __expf(s[cf][1] * 0.125f * wv.y);
                p2 = mm.z ? 0.f : __expf(s[cf][2] * 0.125f * wv.z);
                p3 = mm.w ? 0.f : __expf(s[cf][3] * 0.125f * wv.w);
            }
            den += p0 + p1 + p2 + p3;
            ushort4 pw;
            pw.x = f2bf(p0); pw.y = f2bf(p1); pw.z = f2bf(p2); pw.w = f2bf(p3);
            // P[q=l16][k=cf*16+g*4 .. +3]  (wave-private -> no block barrier needed)
            *reinterpret_cast<ushort4*>(&P[w][l16][cf * 16 + g * 4]) = pw;
        }
        // PV: pf = P[q=l16][ks*32+g*8..+7] (A-fragment), vf = Vt rows d=cf*16+l16
#pragma unroll
        for (int ks = 0; ks < 2; ks++) {
            short8 pf = *reinterpret_cast<const short8*>(&P[w][l16][ks * 32 + g * 8]);
#pragma unroll
            for (int cf = 0; cf < 4; cf++) {
                short8 vf = *reinterpret_cast<const short8*>(
                    Vbh + (size_t)(cf * 16 + l16) * 1024 + kb + ks * 32 + g * 8);
                accO[cf] = __builtin_amdgcn_mfma_f32_16x16x32_bf16(pf, vf, accO[cf], 0, 0, 0);
            }
        }
    }

    // den currently: partial row-sum for q-row l16 over this lane's 16 k-cols per tile
    den += __shfl_xor(den, 16);
    den += __shfl_xor(den, 32);   // lanes with same l16 now hold full row sum

#pragma unroll
    for (int r = 0; r < 4; r++) {
        float dr = __shfl(den, g * 4 + r);   // den for output row g*4+r
        float inv = 1.0f / dr;
#pragma unroll
        for (int cf = 0; cf < 4; cf++) {
            int qrow = qbase + w * 16 + g * 4 + r;
            int col = h * 64 + cf * 16 + l16;
            AO[((size_t)b * 1024 + qrow) * 1024 + col] = f2bf(accO[cf][r] * inv);
        }
    }
}

// ---------- output projection: d_out = AO (bf16 8192x1024) @ Wo + bo (f32 out) ----------
__global__ __launch_bounds__(256) void outproj_kernel(
    const unsigned short* __restrict__ Ain,
    const unsigned short* __restrict__ Wto,
    const float* __restrict__ bo,
    float* __restrict__ Out)
{
    const int tid = threadIdx.x;
    const int w = tid >> 6, l = tid & 63;
    const int l16 = l & 15, g = l >> 4;
    const int rbase = blockIdx.x * 128 + w * 32;
    const int cbase = blockIdx.y * 64;

    f32x4 acc[2][4];
#pragma unroll
    for (int i = 0; i < 2; i++)
#pragma unroll
        for (int j = 0; j < 4; j++) acc[i][j] = (f32x4){0.f, 0.f, 0.f, 0.f};

#pragma unroll 2
    for (int k0 = 0; k0 < 1024; k0 += 32) {
        short8 a[2];
#pragma unroll
        for (int rf = 0; rf < 2; rf++)
            a[rf] = *reinterpret_cast<const short8*>(Ain + (size_t)(rbase + rf * 16 + l16) * 1024 + k0 + g * 8);
        short8 bfr[4];
#pragma unroll
        for (int cf = 0; cf < 4; cf++)
            bfr[cf] = *reinterpret_cast<const short8*>(Wto + (size_t)(cbase + cf * 16 + l16) * 1024 + k0 + g * 8);
#pragma unroll
        for (int rf = 0; rf < 2; rf++)
#pragma unroll
            for (int cf = 0; cf < 4; cf++)
                acc[rf][cf] = __builtin_amdgcn_mfma_f32_16x16x32_bf16(a[rf], bfr[cf], acc[rf][cf], 0, 0, 0);
    }

#pragma unroll
    for (int rf = 0; rf < 2; rf++)
#pragma unroll
        for (int cf = 0; cf < 4; cf++)
#pragma unroll
            for (int r = 0; r < 4; r++) {
                int row = rbase + rf * 16 + g * 4 + r;
                int col = cbase + cf * 16 + l16;
                Out[(size_t)row * 1024 + col] = acc[rf][cf][r] + bo[col];
            }
}

extern "C" void kernel_launch(void* const* d_in, const int* in_sizes, int n_in,
                              void* d_out, int out_size, void* d_ws, size_t ws_size,
                              hipStream_t stream)
{
    const float* queries = (const float*)d_in[0];
    const float* keys    = (const float*)d_in[1];
    const float* values  = (const float*)d_in[2];
    const void*  mask    = d_in[3];
    const float* attw    = (const float*)d_in[4];
    const float* Wq = (const float*)d_in[5];
    const float* bq = (const float*)d_in[6];
    const float* Wk = (const float*)d_in[7];
    const float* bk = (const float*)d_in[8];
    const float* Wv = (const float*)d_in[9];
    const float* bv = (const float*)d_in[10];
    const float* Wo = (const float*)d_in[11];
    const float* bo = (const float*)d_in[12];

    char* ws = (char*)d_ws;
    int* flag = (int*)ws;
    unsigned short* base = (unsigned short*)(ws + 256);
    const size_t M8 = (size_t)8 * 1024 * 1024;   // elements per 16MB bf16 buffer
    unsigned short* Qs  = base;
    unsigned short* Ksb = base + M8;
    unsigned short* Vs  = base + 2 * M8;
    unsigned short* Vtb = base + 3 * M8;
    unsigned short* AO  = base + 4 * M8;
    unsigned short* Wt  = base + 5 * M8;                         // 4 x 1M elements (8 MB)
    unsigned short* Abf = base + 5 * M8 + 4 * 1024 * 1024;       // 3 x 8M elements (48 MB), optional
    const size_t need_abf = 256 + (5 * M8 + 4 * 1024 * 1024 + 3 * M8) * sizeof(unsigned short);
    const bool useAbf = ws_size >= need_abf;

    detect_mask_kernel<<<1, 256, 0, stream>>>((const unsigned int*)mask, flag);
    wconv_kernel<<<dim3(16, 16, 4), 256, 0, stream>>>(Wq, Wk, Wv, Wo, Wt);
    if (useAbf) {
        aconv_kernel<<<dim3(4096, 3), 256, 0, stream>>>(queries, keys, values, Abf);
        proj_bf_kernel<<<dim3(64, 16, 3), 256, 0, stream>>>(Abf, Wt, bq, bk, bv, Qs);
    } else {
        proj_f32_kernel<<<dim3(64, 16, 3), 256, 0, stream>>>(queries, keys, values, Wt, bq, bk, bv, Qs);
    }
    vtrans_kernel<<<dim3(16, 128), 256, 0, stream>>>(Vs, Vtb);
    attn_kernel<<<dim3(16, 16, 8), 256, 0, stream>>>(Qs, Ksb, Vtb, attw, mask, flag, AO);
    outproj_kernel<<<dim3(64, 16), 256, 0, stream>>>(AO, Wt + (size_t)3 * 1024 * 1024, bo, (float*)d_out);
}